// Round 3
// baseline (156.635 us; speedup 1.0000x reference)
//
#include <hip/hip_runtime.h>
#include <cstdint>

#define B_ 4
#define I_ 512
#define T_ 32
#define J_ 256
#define D_ 512
#define DV_ 512
#define KD_ 64
#define TJ_ (T_*J_)      /* 8192 */
#define BI_ (B_*I_)      /* 2048 */
#define MK_ (B_*T_*J_)   /* 32768 */

typedef unsigned short u16;
typedef __attribute__((ext_vector_type(8))) u16 u16x8;
typedef __attribute__((ext_vector_type(4))) u16 u16x4;
typedef __attribute__((ext_vector_type(8))) short bf16x8;
typedef __attribute__((ext_vector_type(4))) float f32x4;

__device__ __forceinline__ u16 f2bf(float f){
  unsigned u = __float_as_uint(f);
  u += 0x7fffu + ((u >> 16) & 1u);
  return (u16)(u >> 16);
}
__device__ __forceinline__ float bf2f(u16 h){ return __uint_as_float(((unsigned)h) << 16); }

// ---------------------------------------------------------------- all 3 weight transposes in one launch
__global__ void k_transpose_w3(const float* __restrict__ Wq, const float* __restrict__ Wk,
                               const float* __restrict__ Wv, u16* __restrict__ wqt,
                               u16* __restrict__ wkt, u16* __restrict__ wvt){
  int gid = blockIdx.x*256 + threadIdx.x;
  if (gid < 32768){
    int n = gid >> 9, k = gid & 511;
    wqt[gid] = f2bf(Wq[(size_t)k*64 + n]);
  } else if (gid < 65536){
    int g = gid - 32768;
    int n = g >> 9, k = g & 511;
    wkt[g] = f2bf(Wk[(size_t)k*64 + n]);
  } else if (gid < 65536 + 262144){
    int g = gid - 65536;
    int n = g >> 9, k = g & 511;
    wvt[g] = f2bf(Wv[(size_t)k*512 + n]);
  }
}

// ---------------------------------------------------------------- memory_y [b][tj][dv] f32 -> Yt [b][dv][tj] bf16
__global__ __launch_bounds__(256) void k_y_transpose(const float* __restrict__ Y, u16* __restrict__ Yt){
  __shared__ __align__(16) u16 tileT[64][72];   // [dv][tj]
  int b = blockIdx.z, k0 = blockIdx.x*64, n0 = blockIdx.y*64;
  int tid = threadIdx.x;
  #pragma unroll
  for (int s=0;s<4;++s){
    int idx = tid + s*256; int r = idx>>4, c4 = idx&15;
    const float4 v = *(const float4*)&Y[((size_t)b*TJ_ + k0 + r)*DV_ + n0 + c4*4];
    tileT[c4*4+0][r] = f2bf(v.x);
    tileT[c4*4+1][r] = f2bf(v.y);
    tileT[c4*4+2][r] = f2bf(v.z);
    tileT[c4*4+3][r] = f2bf(v.w);
  }
  __syncthreads();
  #pragma unroll
  for (int s=0;s<2;++s){
    int idx = tid + s*256; int rn = idx>>3, c8 = idx&7;
    *(u16x8*)&Yt[((size_t)b*DV_ + n0 + rn)*TJ_ + k0 + c8*8] = *(const u16x8*)&tileT[rn][c8*8];
  }
}

// ---------------------------------------------------------------- 64-row-tile GEMM: C[M][N] = A[M][512] * Bt[N][512]^T + bias
template<bool ABF, bool OUTF32>
__global__ __launch_bounds__(256) void k_gemm64(const void* __restrict__ Ap, const u16* __restrict__ Bt,
                                                const float* __restrict__ bias, void* __restrict__ Cp, int N){
  __shared__ __align__(16) u16 As[64][72];
  __shared__ __align__(16) u16 Bs[64][72];
  int tid = threadIdx.x;
  int lane = tid & 63, wv = tid >> 6;
  int lrow = lane & 15, lk = (lane >> 4) * 8;
  int row0 = blockIdx.x * 64, col0 = blockIdx.y * 64;
  f32x4 acc[4];
  #pragma unroll
  for (int j=0;j<4;++j) acc[j] = (f32x4){0.f,0.f,0.f,0.f};

  for (int k0 = 0; k0 < 512; k0 += 64){
    if constexpr (ABF){
      const u16* A = (const u16*)Ap;
      #pragma unroll
      for (int s=0;s<2;++s){
        int idx = tid + s*256; int r = idx>>3, c8 = idx&7;
        *(u16x8*)&As[r][c8*8] = *(const u16x8*)&A[(size_t)(row0+r)*512 + k0 + c8*8];
      }
    } else {
      const float* A = (const float*)Ap;
      #pragma unroll
      for (int s=0;s<4;++s){
        int idx = tid + s*256; int r = idx>>4, c4 = idx&15;
        const float4 v = *(const float4*)&A[(size_t)(row0+r)*512 + k0 + c4*4];
        u16x4 o; o[0]=f2bf(v.x); o[1]=f2bf(v.y); o[2]=f2bf(v.z); o[3]=f2bf(v.w);
        *(u16x4*)&As[r][c4*4] = o;
      }
    }
    #pragma unroll
    for (int s=0;s<2;++s){
      int idx = tid + s*256; int n = idx>>3, c8 = idx&7;
      *(u16x8*)&Bs[n][c8*8] = *(const u16x8*)&Bt[(size_t)(col0+n)*512 + k0 + c8*8];
    }
    __syncthreads();
    #pragma unroll
    for (int kk=0;kk<2;++kk){
      bf16x8 a = *(const bf16x8*)&As[wv*16 + lrow][kk*32 + lk];
      #pragma unroll
      for (int nf=0;nf<4;++nf){
        bf16x8 bb = *(const bf16x8*)&Bs[nf*16 + lrow][kk*32 + lk];
        acc[nf] = __builtin_amdgcn_mfma_f32_16x16x32_bf16(a, bb, acc[nf], 0, 0, 0);
      }
    }
    __syncthreads();
  }
  #pragma unroll
  for (int nf=0;nf<4;++nf)
    #pragma unroll
    for (int r=0;r<4;++r){
      int row = row0 + wv*16 + (lane>>4)*4 + r;
      int col = col0 + nf*16 + lrow;
      float v = acc[nf][r] + (bias ? bias[col] : 0.f);
      if constexpr (OUTF32) ((float*)Cp)[(size_t)row*N + col] = v;
      else ((u16*)Cp)[(size_t)row*N + col] = f2bf(v);
    }
}

// ---------------------------------------------------------------- split-K final GEMM: partial[kc] = ubf * wvt^T over K=128
__global__ __launch_bounds__(256) void k_gemmF(const u16* __restrict__ A, const u16* __restrict__ Bt,
                                               float* __restrict__ Pp){
  __shared__ __align__(16) u16 As[64][72];
  __shared__ __align__(16) u16 Bs[64][72];
  int tid = threadIdx.x;
  int lane = tid & 63, wv = tid >> 6;
  int lrow = lane & 15, lk = (lane >> 4) * 8;
  int row0 = blockIdx.x * 64, col0 = blockIdx.y * 64, kc = blockIdx.z;
  f32x4 acc[4];
  #pragma unroll
  for (int j=0;j<4;++j) acc[j] = (f32x4){0.f,0.f,0.f,0.f};

  #pragma unroll
  for (int it = 0; it < 2; ++it){
    int k0 = kc*128 + it*64;
    #pragma unroll
    for (int s=0;s<2;++s){
      int idx = tid + s*256; int r = idx>>3, c8 = idx&7;
      *(u16x8*)&As[r][c8*8] = *(const u16x8*)&A[(size_t)(row0+r)*512 + k0 + c8*8];
    }
    #pragma unroll
    for (int s=0;s<2;++s){
      int idx = tid + s*256; int n = idx>>3, c8 = idx&7;
      *(u16x8*)&Bs[n][c8*8] = *(const u16x8*)&Bt[(size_t)(col0+n)*512 + k0 + c8*8];
    }
    __syncthreads();
    #pragma unroll
    for (int kk=0;kk<2;++kk){
      bf16x8 a = *(const bf16x8*)&As[wv*16 + lrow][kk*32 + lk];
      #pragma unroll
      for (int nf=0;nf<4;++nf){
        bf16x8 bb = *(const bf16x8*)&Bs[nf*16 + lrow][kk*32 + lk];
        acc[nf] = __builtin_amdgcn_mfma_f32_16x16x32_bf16(a, bb, acc[nf], 0, 0, 0);
      }
    }
    __syncthreads();
  }
  #pragma unroll
  for (int nf=0;nf<4;++nf)
    #pragma unroll
    for (int r=0;r<4;++r){
      int row = row0 + wv*16 + (lane>>4)*4 + r;
      int col = col0 + nf*16 + lrow;
      Pp[(size_t)kc*BI_*DV_ + (size_t)row*DV_ + col] = acc[nf][r];
    }
}

// ---------------------------------------------------------------- out = bias + sum of 4 partials (f32)
__global__ __launch_bounds__(256) void k_out(const float* __restrict__ Pp, const float* __restrict__ bv,
                                             float* __restrict__ out){
  int gid = blockIdx.x*256 + threadIdx.x;   // float4 index over BI_*DV_/4
  const float4* u = (const float4*)Pp;
  const size_t stride = (size_t)BI_*DV_/4;
  float4 s = u[gid];
  #pragma unroll
  for (int c=1;c<4;++c){
    float4 v = u[gid + (size_t)c*stride];
    s.x += v.x; s.y += v.y; s.z += v.z; s.w += v.w;
  }
  const float4 b = *(const float4*)&bv[(gid & 127)*4];
  s.x += b.x; s.y += b.y; s.z += b.z; s.w += b.w;
  ((float4*)out)[gid] = s;
}

// ---------------------------------------------------------------- scores: per (b,t,i-tile of 64): S=Q*K^T, stats, P
__global__ __launch_bounds__(256) void k_score(const u16* __restrict__ Qbf, const u16* __restrict__ Kbf,
                                               u16* __restrict__ P, float* __restrict__ mb, float* __restrict__ zb){
  __shared__ __align__(16) u16 Qs[64][72];
  __shared__ __align__(16) u16 Ks[256][72];   // reused as Ps[64][264] after MFMA
  __shared__ float smax[4][64];
  __shared__ float ssum[4][64];
  __shared__ float mrow[64];
  int tid = threadIdx.x;
  int i0 = blockIdx.x*64, t = blockIdx.y, b = blockIdx.z;
  int lane = tid & 63, wv = tid >> 6;
  int lrow = lane & 15, lk = (lane >> 4) * 8;

  #pragma unroll
  for (int s=0;s<2;++s){
    int idx = tid + s*256; int r = idx>>3, c8 = idx&7;
    *(u16x8*)&Qs[r][c8*8] = *(const u16x8*)&Qbf[((size_t)b*I_ + i0 + r)*KD_ + c8*8];
  }
  #pragma unroll
  for (int s=0;s<8;++s){
    int idx = tid + s*256; int r = idx>>3, c8 = idx&7;
    *(u16x8*)&Ks[r][c8*8] = *(const u16x8*)&Kbf[(((size_t)b*T_ + t)*J_ + r)*KD_ + c8*8];
  }
  __syncthreads();

  f32x4 acc[4][4];
  #pragma unroll
  for (int i=0;i<4;++i)
    #pragma unroll
    for (int j=0;j<4;++j) acc[i][j] = (f32x4){0.f,0.f,0.f,0.f};

  #pragma unroll
  for (int kk=0;kk<2;++kk){
    bf16x8 a[4], bb[4];
    #pragma unroll
    for (int mf=0;mf<4;++mf) a[mf] = *(const bf16x8*)&Qs[mf*16 + lrow][kk*32 + lk];
    #pragma unroll
    for (int nf=0;nf<4;++nf) bb[nf] = *(const bf16x8*)&Ks[wv*64 + nf*16 + lrow][kk*32 + lk];
    #pragma unroll
    for (int mf=0;mf<4;++mf)
      #pragma unroll
      for (int nf=0;nf<4;++nf)
        acc[mf][nf] = __builtin_amdgcn_mfma_f32_16x16x32_bf16(a[mf], bb[nf], acc[mf][nf], 0, 0, 0);
  }

  #pragma unroll
  for (int mf=0;mf<4;++mf)
    #pragma unroll
    for (int r=0;r<4;++r){
      float v = acc[mf][0][r];
      #pragma unroll
      for (int nf=1;nf<4;++nf) v = fmaxf(v, acc[mf][nf][r]);
      v = fmaxf(v, __shfl_xor(v, 1));
      v = fmaxf(v, __shfl_xor(v, 2));
      v = fmaxf(v, __shfl_xor(v, 4));
      v = fmaxf(v, __shfl_xor(v, 8));
      if (lrow == 0) smax[wv][mf*16 + (lane>>4)*4 + r] = v;
    }
  __syncthreads();
  if (tid < 64){
    float m = fmaxf(fmaxf(smax[0][tid], smax[1][tid]), fmaxf(smax[2][tid], smax[3][tid]));
    mrow[tid] = m;
    mb[((size_t)b*T_ + t)*I_ + i0 + tid] = m;
  }
  __syncthreads();

  #pragma unroll
  for (int mf=0;mf<4;++mf)
    #pragma unroll
    for (int r=0;r<4;++r){
      int row = mf*16 + (lane>>4)*4 + r;
      float M = mrow[row];
      float ssm = 0.f;
      #pragma unroll
      for (int nf=0;nf<4;++nf){
        float p = __expf(0.125f*(acc[mf][nf][r] - M));
        acc[mf][nf][r] = p;
        ssm += p;
      }
      ssm += __shfl_xor(ssm, 1);
      ssm += __shfl_xor(ssm, 2);
      ssm += __shfl_xor(ssm, 4);
      ssm += __shfl_xor(ssm, 8);
      if (lrow == 0) ssum[wv][row] = ssm;
    }
  __syncthreads();
  if (tid < 64){
    float z = ssum[0][tid] + ssum[1][tid] + ssum[2][tid] + ssum[3][tid];
    zb[((size_t)b*T_ + t)*I_ + i0 + tid] = z;
  }

  // pack P into LDS (reuse Ks region), then coalesced u16x8 global writes
  u16* Ps = &Ks[0][0];              // stride 264 u16, 64 rows -> 16896 u16 <= 18432
  #pragma unroll
  for (int mf=0;mf<4;++mf)
    #pragma unroll
    for (int nf=0;nf<4;++nf)
      #pragma unroll
      for (int r=0;r<4;++r){
        int row = mf*16 + (lane>>4)*4 + r;
        int col = wv*64 + nf*16 + lrow;
        Ps[row*264 + col] = f2bf(acc[mf][nf][r]);
      }
  __syncthreads();
  #pragma unroll
  for (int s=0;s<8;++s){
    int idx = tid + s*256; int r = idx>>5, c8 = idx&31;
    *(u16x8*)&P[(((size_t)b*T_ + t)*I_ + i0 + r)*J_ + c8*8] = *(const u16x8*)&Ps[r*264 + c8*8];
  }
}

// ---------------------------------------------------------------- level-2 softmax over t -> c[b,t,i] = w_t/(W*z)
__global__ __launch_bounds__(256) void k_level2(const float* __restrict__ mb, const float* __restrict__ zb,
                                                float* __restrict__ cb){
  int gid = blockIdx.x*256 + threadIdx.x;   // 0..2047
  int b = gid >> 9, i = gid & 511;
  float w[T_];
  float lmax = -3.0e38f;
  #pragma unroll
  for (int t=0;t<T_;++t){
    float mt = 0.125f * mb[((size_t)b*T_ + t)*I_ + i];
    w[t] = mt;
    lmax = fmaxf(lmax, mt);
  }
  float W = 0.f;
  #pragma unroll
  for (int t=0;t<T_;++t){ float e = __expf(w[t] - lmax); w[t] = e; W += e; }
  float inv = 1.f / W;
  #pragma unroll
  for (int t=0;t<T_;++t)
    cb[((size_t)b*T_ + t)*I_ + i] = w[t] * inv / zb[((size_t)b*T_ + t)*I_ + i];
}

// ---------------------------------------------------------------- U = sum_t c_t * (P_t @ Y_t), K split into CH chunks
template<int CH>
__global__ __launch_bounds__(256,2) void k_passB(const u16* __restrict__ P, const float* __restrict__ cb,
                                                 const u16* __restrict__ Yt, float* __restrict__ Up){
  constexpr int TPC = T_/CH;              // t's per chunk
  __shared__ __align__(16) u16 As[128][72];
  __shared__ __align__(16) u16 Bs[128][72];
  __shared__ float cs[TPC][128];
  int tid = threadIdx.x;
  int lane = tid & 63, wv = tid >> 6, wm = wv >> 1, wn = wv & 1;
  int lrow = lane & 15, lk = (lane >> 4) * 8;
  int i0 = blockIdx.x*128, n0 = blockIdx.y*128;
  int b = blockIdx.z / CH, ch = blockIdx.z % CH;

  for (int idx = tid; idx < TPC*128; idx += 256){
    int tt = idx >> 7, r = idx & 127;
    cs[tt][r] = cb[((size_t)b*T_ + ch*TPC + tt)*I_ + i0 + r];
  }

  f32x4 acc[4][4];
  #pragma unroll
  for (int i=0;i<4;++i)
    #pragma unroll
    for (int j=0;j<4;++j) acc[i][j] = (f32x4){0.f,0.f,0.f,0.f};

  for (int tt = 0; tt < TPC; ++tt){
    int t = ch*TPC + tt;
    f32x4 at[4][4];
    #pragma unroll
    for (int i=0;i<4;++i)
      #pragma unroll
      for (int j=0;j<4;++j) at[i][j] = (f32x4){0.f,0.f,0.f,0.f};

    for (int st = 0; st < 4; ++st){
      int j0 = st*64;
      #pragma unroll
      for (int s=0;s<4;++s){
        int idx = tid + s*256; int r = idx>>3, c8 = idx&7;
        *(u16x8*)&As[r][c8*8] = *(const u16x8*)&P[(((size_t)b*T_ + t)*I_ + i0 + r)*J_ + j0 + c8*8];
      }
      #pragma unroll
      for (int s=0;s<4;++s){
        int idx = tid + s*256; int n = idx>>3, c8 = idx&7;
        *(u16x8*)&Bs[n][c8*8] = *(const u16x8*)&Yt[((size_t)b*DV_ + n0 + n)*TJ_ + t*J_ + j0 + c8*8];
      }
      __syncthreads();
      #pragma unroll
      for (int kk=0;kk<2;++kk){
        bf16x8 a[4], bb[4];
        #pragma unroll
        for (int mf=0;mf<4;++mf) a[mf] = *(const bf16x8*)&As[wm*64 + mf*16 + lrow][kk*32 + lk];
        #pragma unroll
        for (int nf=0;nf<4;++nf) bb[nf] = *(const bf16x8*)&Bs[wn*64 + nf*16 + lrow][kk*32 + lk];
        #pragma unroll
        for (int mf=0;mf<4;++mf)
          #pragma unroll
          for (int nf=0;nf<4;++nf)
            at[mf][nf] = __builtin_amdgcn_mfma_f32_16x16x32_bf16(a[mf], bb[nf], at[mf][nf], 0, 0, 0);
      }
      __syncthreads();
    }
    #pragma unroll
    for (int mf=0;mf<4;++mf)
      #pragma unroll
      for (int r=0;r<4;++r){
        float c = cs[tt][wm*64 + mf*16 + (lane>>4)*4 + r];
        #pragma unroll
        for (int nf=0;nf<4;++nf)
          acc[mf][nf][r] += c * at[mf][nf][r];
      }
  }

  #pragma unroll
  for (int mf=0;mf<4;++mf)
    #pragma unroll
    for (int nf=0;nf<4;++nf)
      #pragma unroll
      for (int r=0;r<4;++r){
        int row = i0 + wm*64 + mf*16 + (lane>>4)*4 + r;
        int col = n0 + wn*64 + nf*16 + lrow;
        Up[(size_t)ch*BI_*DV_ + ((size_t)b*I_ + row)*DV_ + col] = acc[mf][nf][r];
      }
}

// ---------------------------------------------------------------- sum CH partials -> U bf16
template<int CH>
__global__ __launch_bounds__(256) void k_reduce_u(const float* __restrict__ Up, u16* __restrict__ Ubf){
  int gid = blockIdx.x*256 + threadIdx.x;   // float4 index
  const float4* u = (const float4*)Up;
  const size_t stride = (size_t)BI_*DV_/4;
  float4 s = u[gid];
  #pragma unroll
  for (int c=1;c<CH;++c){
    float4 v = u[gid + (size_t)c*stride];
    s.x += v.x; s.y += v.y; s.z += v.z; s.w += v.w;
  }
  u16x4 o; o[0]=f2bf(s.x); o[1]=f2bf(s.y); o[2]=f2bf(s.z); o[3]=f2bf(s.w);
  *(u16x4*)&Ubf[(size_t)gid*4] = o;
}

// ----------------------------------------------------------------
extern "C" void kernel_launch(void* const* d_in, const int* in_sizes, int n_in,
                              void* d_out, int out_size, void* d_ws, size_t ws_size,
                              hipStream_t stream){
  const float* input_seq = (const float*)d_in[0];
  const float* memory_x  = (const float*)d_in[1];
  const float* memory_y  = (const float*)d_in[2];
  const float* Wq = (const float*)d_in[3];
  const float* bq = (const float*)d_in[4];
  const float* Wk = (const float*)d_in[5];
  const float* bk = (const float*)d_in[6];
  const float* Wv = (const float*)d_in[7];
  const float* bv = (const float*)d_in[8];
  float* out = (float*)d_out;

  char* ws = (char*)d_ws;
  size_t off = 0;
  auto alloc = [&](size_t bytes)->void*{
    void* p = ws + off; off += (bytes + 255) & ~(size_t)255; return p;
  };
  u16*   wqt = (u16*)  alloc((size_t)KD_*D_*2);
  u16*   wkt = (u16*)  alloc((size_t)KD_*D_*2);
  u16*   wvt = (u16*)  alloc((size_t)DV_*DV_*2);
  u16*   qbf = (u16*)  alloc((size_t)BI_*KD_*2);
  u16*   kbf = (u16*)  alloc((size_t)MK_*KD_*2);
  u16*   yt  = (u16*)  alloc((size_t)B_*DV_*TJ_*2);
  u16*   Pb  = (u16*)  alloc((size_t)B_*T_*I_*J_*2);
  float* mb  = (float*)alloc((size_t)B_*T_*I_*4);
  float* zb  = (float*)alloc((size_t)B_*T_*I_*4);
  float* cb  = (float*)alloc((size_t)B_*T_*I_*4);
  u16*   ubf = (u16*)  alloc((size_t)BI_*DV_*2);
  size_t part = (size_t)BI_*DV_*4;
  float* Fp  = (float*)alloc(4*part);          // final-gemm split-K partials
  int CH = (off + 8*part <= ws_size) ? 8 : 4;
  float* Up  = (float*)alloc((size_t)CH*part);

  k_transpose_w3<<<(2*D_*KD_ + DV_*DV_ + 255)/256, 256, 0, stream>>>(Wq, Wk, Wv, wqt, wkt, wvt);
  k_y_transpose<<<dim3(TJ_/64, DV_/64, B_), 256, 0, stream>>>(memory_y, yt);
  k_gemm64<false,false><<<dim3(BI_/64, 1), 256, 0, stream>>>(input_seq, wqt, bq, qbf, KD_);
  k_gemm64<false,false><<<dim3(MK_/64, 1), 256, 0, stream>>>(memory_x, wkt, bk, kbf, KD_);
  k_score<<<dim3(I_/64, T_, B_), 256, 0, stream>>>(qbf, kbf, Pb, mb, zb);
  k_level2<<<BI_/256, 256, 0, stream>>>(mb, zb, cb);
  if (CH == 8){
    k_passB<8><<<dim3(I_/128, DV_/128, B_*8), 256, 0, stream>>>(Pb, cb, yt, Up);
    k_reduce_u<8><<<(BI_*DV_/4)/256, 256, 0, stream>>>(Up, ubf);
  } else {
    k_passB<4><<<dim3(I_/128, DV_/128, B_*4), 256, 0, stream>>>(Pb, cb, yt, Up);
    k_reduce_u<4><<<(BI_*DV_/4)/256, 256, 0, stream>>>(Up, ubf);
  }
  k_gemmF<<<dim3(BI_/64, DV_/64, 4), 256, 0, stream>>>(ubf, wvt, Fp);
  k_out<<<(BI_*DV_/4)/256, 256, 0, stream>>>(Fp, bv, out);
}

// Round 4
// 117.006 us; speedup vs baseline: 1.3387x; 1.3387x over previous
//
#include <hip/hip_runtime.h>
#include <cstdint>

#define B_ 4
#define I_ 512
#define T_ 32
#define J_ 256
#define D_ 512
#define DV_ 512
#define KD_ 64
#define TJ_ (T_*J_)      /* 8192 */
#define BI_ (B_*I_)      /* 2048 */
#define MK_ (B_*T_*J_)   /* 32768 */

typedef unsigned short u16;
typedef __attribute__((ext_vector_type(8))) u16 u16x8;
typedef __attribute__((ext_vector_type(4))) u16 u16x4;
typedef __attribute__((ext_vector_type(8))) short bf16x8;
typedef __attribute__((ext_vector_type(4))) float f32x4;

__device__ __forceinline__ u16 f2bf(float f){
  unsigned u = __float_as_uint(f);
  u += 0x7fffu + ((u >> 16) & 1u);
  return (u16)(u >> 16);
}
__device__ __forceinline__ float bf2f(u16 h){ return __uint_as_float(((unsigned)h) << 16); }

// ---------------------------------------------------------------- prep: Y transpose tiles + all 3 weight transposes, one launch
// blocks [0,4096): y-transpose 64x64 tiles. blocks [4096,5376): weight transposes.
__global__ __launch_bounds__(256) void k_prep(const float* __restrict__ Y, u16* __restrict__ Yt,
                                              const float* __restrict__ Wq, const float* __restrict__ Wk,
                                              const float* __restrict__ Wv, u16* __restrict__ wqt,
                                              u16* __restrict__ wkt, u16* __restrict__ wvt){
  __shared__ __align__(16) u16 tileT[64][72];
  int bid = blockIdx.x;
  int tid = threadIdx.x;
  if (bid < 4096){
    int kx = bid & 127, ny = (bid >> 7) & 7, b = bid >> 10;
    int k0 = kx*64, n0 = ny*64;
    #pragma unroll
    for (int s=0;s<4;++s){
      int idx = tid + s*256; int r = idx>>4, c4 = idx&15;
      const float4 v = *(const float4*)&Y[((size_t)b*TJ_ + k0 + r)*DV_ + n0 + c4*4];
      tileT[c4*4+0][r] = f2bf(v.x);
      tileT[c4*4+1][r] = f2bf(v.y);
      tileT[c4*4+2][r] = f2bf(v.z);
      tileT[c4*4+3][r] = f2bf(v.w);
    }
    __syncthreads();
    #pragma unroll
    for (int s=0;s<2;++s){
      int idx = tid + s*256; int rn = idx>>3, c8 = idx&7;
      *(u16x8*)&Yt[((size_t)b*DV_ + n0 + rn)*TJ_ + k0 + c8*8] = *(const u16x8*)&tileT[rn][c8*8];
    }
  } else {
    int gid = (bid - 4096)*256 + tid;
    if (gid < 32768){
      int n = gid >> 9, k = gid & 511;
      wqt[gid] = f2bf(Wq[(size_t)k*64 + n]); (void)n;
    } else if (gid < 65536){
      int g = gid - 32768;
      int n = g >> 9, k = g & 511;
      wkt[g] = f2bf(Wk[(size_t)k*64 + n]); (void)n;
    } else {
      int g = gid - 65536;
      int n = g >> 9, k = g & 511;
      wvt[g] = f2bf(Wv[(size_t)k*512 + n]); (void)n;
    }
  }
}

// ---------------------------------------------------------------- merged Q+K projections: C[M][64] = A[M][512]*Wt[64][512]^T + b
// blocks [0,512): K-proj over memory_x; blocks [512,544): Q-proj over input_seq.
__global__ __launch_bounds__(256) void k_proj(const float* __restrict__ mx, const float* __restrict__ iseq,
                                              const u16* __restrict__ wkt, const u16* __restrict__ wqt,
                                              const float* __restrict__ bk, const float* __restrict__ bq,
                                              u16* __restrict__ kbf, u16* __restrict__ qbf){
  __shared__ __align__(16) u16 As[64][72];
  __shared__ __align__(16) u16 Bs[64][72];
  int bid = blockIdx.x;
  const float* A; const u16* Bt; const float* bias; u16* C; int row0;
  if (bid < 512){ A = mx;   Bt = wkt; bias = bk; C = kbf; row0 = bid*64; }
  else          { A = iseq; Bt = wqt; bias = bq; C = qbf; row0 = (bid-512)*64; }
  int tid = threadIdx.x;
  int lane = tid & 63, wv = tid >> 6;
  int lrow = lane & 15, lk = (lane >> 4) * 8;
  f32x4 acc[4];
  #pragma unroll
  for (int j=0;j<4;++j) acc[j] = (f32x4){0.f,0.f,0.f,0.f};

  for (int k0 = 0; k0 < 512; k0 += 64){
    #pragma unroll
    for (int s=0;s<4;++s){
      int idx = tid + s*256; int r = idx>>4, c4 = idx&15;
      const float4 v = *(const float4*)&A[(size_t)(row0+r)*512 + k0 + c4*4];
      u16x4 o; o[0]=f2bf(v.x); o[1]=f2bf(v.y); o[2]=f2bf(v.z); o[3]=f2bf(v.w);
      *(u16x4*)&As[r][c4*4] = o;
    }
    #pragma unroll
    for (int s=0;s<2;++s){
      int idx = tid + s*256; int n = idx>>3, c8 = idx&7;
      *(u16x8*)&Bs[n][c8*8] = *(const u16x8*)&Bt[(size_t)n*512 + k0 + c8*8];
    }
    __syncthreads();
    #pragma unroll
    for (int kk=0;kk<2;++kk){
      bf16x8 a = *(const bf16x8*)&As[wv*16 + lrow][kk*32 + lk];
      #pragma unroll
      for (int nf=0;nf<4;++nf){
        bf16x8 bb = *(const bf16x8*)&Bs[nf*16 + lrow][kk*32 + lk];
        acc[nf] = __builtin_amdgcn_mfma_f32_16x16x32_bf16(a, bb, acc[nf], 0, 0, 0);
      }
    }
    __syncthreads();
  }
  #pragma unroll
  for (int nf=0;nf<4;++nf)
    #pragma unroll
    for (int r=0;r<4;++r){
      int row = row0 + wv*16 + (lane>>4)*4 + r;
      int col = nf*16 + lrow;
      C[(size_t)row*64 + col] = f2bf(acc[nf][r] + bias[col]);
    }
}

// ---------------------------------------------------------------- scores: per (b,t,i-tile of 64): S=Q*K^T, stats, P
__global__ __launch_bounds__(256) void k_score(const u16* __restrict__ Qbf, const u16* __restrict__ Kbf,
                                               u16* __restrict__ P, float* __restrict__ mb, float* __restrict__ zb){
  __shared__ __align__(16) u16 Qs[64][72];
  __shared__ __align__(16) u16 Ks[256][72];   // reused as Ps[64][264] after MFMA
  __shared__ float smax[4][64];
  __shared__ float ssum[4][64];
  __shared__ float mrow[64];
  int tid = threadIdx.x;
  int i0 = blockIdx.x*64, t = blockIdx.y, b = blockIdx.z;
  int lane = tid & 63, wv = tid >> 6;
  int lrow = lane & 15, lk = (lane >> 4) * 8;

  #pragma unroll
  for (int s=0;s<2;++s){
    int idx = tid + s*256; int r = idx>>3, c8 = idx&7;
    *(u16x8*)&Qs[r][c8*8] = *(const u16x8*)&Qbf[((size_t)b*I_ + i0 + r)*KD_ + c8*8];
  }
  #pragma unroll
  for (int s=0;s<8;++s){
    int idx = tid + s*256; int r = idx>>3, c8 = idx&7;
    *(u16x8*)&Ks[r][c8*8] = *(const u16x8*)&Kbf[(((size_t)b*T_ + t)*J_ + r)*KD_ + c8*8];
  }
  __syncthreads();

  f32x4 acc[4][4];
  #pragma unroll
  for (int i=0;i<4;++i)
    #pragma unroll
    for (int j=0;j<4;++j) acc[i][j] = (f32x4){0.f,0.f,0.f,0.f};

  #pragma unroll
  for (int kk=0;kk<2;++kk){
    bf16x8 a[4], bb[4];
    #pragma unroll
    for (int mf=0;mf<4;++mf) a[mf] = *(const bf16x8*)&Qs[mf*16 + lrow][kk*32 + lk];
    #pragma unroll
    for (int nf=0;nf<4;++nf) bb[nf] = *(const bf16x8*)&Ks[wv*64 + nf*16 + lrow][kk*32 + lk];
    #pragma unroll
    for (int mf=0;mf<4;++mf)
      #pragma unroll
      for (int nf=0;nf<4;++nf)
        acc[mf][nf] = __builtin_amdgcn_mfma_f32_16x16x32_bf16(a[mf], bb[nf], acc[mf][nf], 0, 0, 0);
  }

  #pragma unroll
  for (int mf=0;mf<4;++mf)
    #pragma unroll
    for (int r=0;r<4;++r){
      float v = acc[mf][0][r];
      #pragma unroll
      for (int nf=1;nf<4;++nf) v = fmaxf(v, acc[mf][nf][r]);
      v = fmaxf(v, __shfl_xor(v, 1));
      v = fmaxf(v, __shfl_xor(v, 2));
      v = fmaxf(v, __shfl_xor(v, 4));
      v = fmaxf(v, __shfl_xor(v, 8));
      if (lrow == 0) smax[wv][mf*16 + (lane>>4)*4 + r] = v;
    }
  __syncthreads();
  if (tid < 64){
    float m = fmaxf(fmaxf(smax[0][tid], smax[1][tid]), fmaxf(smax[2][tid], smax[3][tid]));
    mrow[tid] = m;
    mb[((size_t)b*T_ + t)*I_ + i0 + tid] = m;
  }
  __syncthreads();

  #pragma unroll
  for (int mf=0;mf<4;++mf)
    #pragma unroll
    for (int r=0;r<4;++r){
      int row = mf*16 + (lane>>4)*4 + r;
      float M = mrow[row];
      float ssm = 0.f;
      #pragma unroll
      for (int nf=0;nf<4;++nf){
        float p = __expf(0.125f*(acc[mf][nf][r] - M));
        acc[mf][nf][r] = p;
        ssm += p;
      }
      ssm += __shfl_xor(ssm, 1);
      ssm += __shfl_xor(ssm, 2);
      ssm += __shfl_xor(ssm, 4);
      ssm += __shfl_xor(ssm, 8);
      if (lrow == 0) ssum[wv][row] = ssm;
    }
  __syncthreads();
  if (tid < 64){
    float z = ssum[0][tid] + ssum[1][tid] + ssum[2][tid] + ssum[3][tid];
    zb[((size_t)b*T_ + t)*I_ + i0 + tid] = z;
  }

  u16* Ps = &Ks[0][0];              // stride 264 u16
  #pragma unroll
  for (int mf=0;mf<4;++mf)
    #pragma unroll
    for (int nf=0;nf<4;++nf)
      #pragma unroll
      for (int r=0;r<4;++r){
        int row = mf*16 + (lane>>4)*4 + r;
        int col = wv*64 + nf*16 + lrow;
        Ps[row*264 + col] = f2bf(acc[mf][nf][r]);
      }
  __syncthreads();
  #pragma unroll
  for (int s=0;s<8;++s){
    int idx = tid + s*256; int r = idx>>5, c8 = idx&31;
    *(u16x8*)&P[(((size_t)b*T_ + t)*I_ + i0 + r)*J_ + c8*8] = *(const u16x8*)&Ps[r*264 + c8*8];
  }
}

// ---------------------------------------------------------------- U = sum_t c_t*(P_t @ Y_t); level-2 softmax computed in-block.
// bf16 partials per K-chunk. XCD-swizzled 1D grid.
template<int CH>
__global__ __launch_bounds__(256,2) void k_passB(const u16* __restrict__ P, const float* __restrict__ mbp,
                                                 const float* __restrict__ zbp, const u16* __restrict__ Yt,
                                                 u16* __restrict__ Up){
  constexpr int TPC = T_/CH;
  __shared__ __align__(16) u16 As[128][72];
  __shared__ __align__(16) u16 Bs[128][72];
  __shared__ float cs[TPC][128];
  int tid = threadIdx.x;
  int lane = tid & 63, wv = tid >> 6, wm = wv >> 1, wn = wv & 1;
  int lrow = lane & 15, lk = (lane >> 4) * 8;

  // XCD swizzle: 16 blocks sharing a (b,ch) chunk land on one XCD
  int NWG = 16*B_*CH;                    // 4 i-tiles x 4 n-tiles x B*CH
  int per = NWG >> 3;
  int logical = (blockIdx.x & 7)*per + (blockIdx.x >> 3);
  int group = logical >> 4, within = logical & 15;
  int ix = within & 3, ny = within >> 2;
  int b = group / CH, ch = group % CH;
  int i0 = ix*128, n0 = ny*128;

  // level-2 softmax over t for this i-slab
  if (tid < 128){
    int i = i0 + tid;
    float w[T_];
    float lmax = -3.0e38f;
    #pragma unroll
    for (int t=0;t<T_;++t){
      float mt = 0.125f * mbp[((size_t)b*T_ + t)*I_ + i];
      w[t] = mt;
      lmax = fmaxf(lmax, mt);
    }
    float W = 0.f;
    #pragma unroll
    for (int t=0;t<T_;++t){ float e = __expf(w[t] - lmax); w[t] = e; W += e; }
    float inv = 1.f / W;
    #pragma unroll
    for (int tt=0;tt<TPC;++tt)
      cs[tt][tid] = w[ch*TPC+tt] * inv / zbp[((size_t)b*T_ + ch*TPC + tt)*I_ + i];
  }
  __syncthreads();

  f32x4 acc[4][4];
  #pragma unroll
  for (int i=0;i<4;++i)
    #pragma unroll
    for (int j=0;j<4;++j) acc[i][j] = (f32x4){0.f,0.f,0.f,0.f};

  for (int tt = 0; tt < TPC; ++tt){
    int t = ch*TPC + tt;
    f32x4 at[4][4];
    #pragma unroll
    for (int i=0;i<4;++i)
      #pragma unroll
      for (int j=0;j<4;++j) at[i][j] = (f32x4){0.f,0.f,0.f,0.f};

    for (int st = 0; st < 4; ++st){
      int j0 = st*64;
      #pragma unroll
      for (int s=0;s<4;++s){
        int idx = tid + s*256; int r = idx>>3, c8 = idx&7;
        *(u16x8*)&As[r][c8*8] = *(const u16x8*)&P[(((size_t)b*T_ + t)*I_ + i0 + r)*J_ + j0 + c8*8];
      }
      #pragma unroll
      for (int s=0;s<4;++s){
        int idx = tid + s*256; int n = idx>>3, c8 = idx&7;
        *(u16x8*)&Bs[n][c8*8] = *(const u16x8*)&Yt[((size_t)b*DV_ + n0 + n)*TJ_ + t*J_ + j0 + c8*8];
      }
      __syncthreads();
      #pragma unroll
      for (int kk=0;kk<2;++kk){
        bf16x8 a[4], bb[4];
        #pragma unroll
        for (int mf=0;mf<4;++mf) a[mf] = *(const bf16x8*)&As[wm*64 + mf*16 + lrow][kk*32 + lk];
        #pragma unroll
        for (int nf=0;nf<4;++nf) bb[nf] = *(const bf16x8*)&Bs[wn*64 + nf*16 + lrow][kk*32 + lk];
        #pragma unroll
        for (int mf=0;mf<4;++mf)
          #pragma unroll
          for (int nf=0;nf<4;++nf)
            at[mf][nf] = __builtin_amdgcn_mfma_f32_16x16x32_bf16(a[mf], bb[nf], at[mf][nf], 0, 0, 0);
      }
      __syncthreads();
    }
    #pragma unroll
    for (int mf=0;mf<4;++mf)
      #pragma unroll
      for (int r=0;r<4;++r){
        float c = cs[tt][wm*64 + mf*16 + (lane>>4)*4 + r];
        #pragma unroll
        for (int nf=0;nf<4;++nf)
          acc[mf][nf][r] += c * at[mf][nf][r];
      }
  }

  #pragma unroll
  for (int mf=0;mf<4;++mf)
    #pragma unroll
    for (int nf=0;nf<4;++nf)
      #pragma unroll
      for (int r=0;r<4;++r){
        int row = i0 + wm*64 + mf*16 + (lane>>4)*4 + r;
        int col = n0 + wn*64 + nf*16 + lrow;
        Up[(size_t)ch*BI_*DV_ + ((size_t)b*I_ + row)*DV_ + col] = f2bf(acc[mf][nf][r]);
      }
}

// ---------------------------------------------------------------- sum CH bf16 partials -> U bf16
template<int CH>
__global__ __launch_bounds__(256) void k_reduce_u(const u16* __restrict__ Up, u16* __restrict__ Ubf){
  int gid = blockIdx.x*256 + threadIdx.x;   // u16x8 index over BI_*DV_/8
  const size_t stride = (size_t)BI_*DV_;
  float s[8] = {0,0,0,0,0,0,0,0};
  #pragma unroll
  for (int c=0;c<CH;++c){
    u16x8 v = *(const u16x8*)&Up[(size_t)c*stride + (size_t)gid*8];
    #pragma unroll
    for (int e=0;e<8;++e) s[e] += bf2f(v[e]);
  }
  u16x8 o;
  #pragma unroll
  for (int e=0;e<8;++e) o[e] = f2bf(s[e]);
  *(u16x8*)&Ubf[(size_t)gid*8] = o;
}

// ---------------------------------------------------------------- split-K final GEMM: partial[kc] = ubf * wvt^T over K=128
__global__ __launch_bounds__(256) void k_gemmF(const u16* __restrict__ A, const u16* __restrict__ Bt,
                                               float* __restrict__ Pp){
  __shared__ __align__(16) u16 As[64][72];
  __shared__ __align__(16) u16 Bs[64][72];
  int tid = threadIdx.x;
  int lane = tid & 63, wv = tid >> 6;
  int lrow = lane & 15, lk = (lane >> 4) * 8;
  int row0 = blockIdx.x * 64, col0 = blockIdx.y * 64, kc = blockIdx.z;
  f32x4 acc[4];
  #pragma unroll
  for (int j=0;j<4;++j) acc[j] = (f32x4){0.f,0.f,0.f,0.f};

  #pragma unroll
  for (int it = 0; it < 2; ++it){
    int k0 = kc*128 + it*64;
    #pragma unroll
    for (int s=0;s<2;++s){
      int idx = tid + s*256; int r = idx>>3, c8 = idx&7;
      *(u16x8*)&As[r][c8*8] = *(const u16x8*)&A[(size_t)(row0+r)*512 + k0 + c8*8];
    }
    #pragma unroll
    for (int s=0;s<2;++s){
      int idx = tid + s*256; int n = idx>>3, c8 = idx&7;
      *(u16x8*)&Bs[n][c8*8] = *(const u16x8*)&Bt[(size_t)(col0+n)*512 + k0 + c8*8];
    }
    __syncthreads();
    #pragma unroll
    for (int kk=0;kk<2;++kk){
      bf16x8 a = *(const bf16x8*)&As[wv*16 + lrow][kk*32 + lk];
      #pragma unroll
      for (int nf=0;nf<4;++nf){
        bf16x8 bb = *(const bf16x8*)&Bs[nf*16 + lrow][kk*32 + lk];
        acc[nf] = __builtin_amdgcn_mfma_f32_16x16x32_bf16(a, bb, acc[nf], 0, 0, 0);
      }
    }
    __syncthreads();
  }
  #pragma unroll
  for (int nf=0;nf<4;++nf)
    #pragma unroll
    for (int r=0;r<4;++r){
      int row = row0 + wv*16 + (lane>>4)*4 + r;
      int col = col0 + nf*16 + lrow;
      Pp[(size_t)kc*BI_*DV_ + (size_t)row*DV_ + col] = acc[nf][r];
    }
}

// ---------------------------------------------------------------- out = bias + sum of 4 partials (f32)
__global__ __launch_bounds__(256) void k_out(const float* __restrict__ Pp, const float* __restrict__ bv,
                                             float* __restrict__ out){
  int gid = blockIdx.x*256 + threadIdx.x;   // float4 index over BI_*DV_/4
  const float4* u = (const float4*)Pp;
  const size_t stride = (size_t)BI_*DV_/4;
  float4 s = u[gid];
  #pragma unroll
  for (int c=1;c<4;++c){
    float4 v = u[gid + (size_t)c*stride];
    s.x += v.x; s.y += v.y; s.z += v.z; s.w += v.w;
  }
  const float4 b = *(const float4*)&bv[(gid & 127)*4];
  s.x += b.x; s.y += b.y; s.z += b.z; s.w += b.w;
  ((float4*)out)[gid] = s;
}

// ----------------------------------------------------------------
extern "C" void kernel_launch(void* const* d_in, const int* in_sizes, int n_in,
                              void* d_out, int out_size, void* d_ws, size_t ws_size,
                              hipStream_t stream){
  const float* input_seq = (const float*)d_in[0];
  const float* memory_x  = (const float*)d_in[1];
  const float* memory_y  = (const float*)d_in[2];
  const float* Wq = (const float*)d_in[3];
  const float* bq = (const float*)d_in[4];
  const float* Wk = (const float*)d_in[5];
  const float* bk = (const float*)d_in[6];
  const float* Wv = (const float*)d_in[7];
  const float* bv = (const float*)d_in[8];
  float* out = (float*)d_out;

  char* ws = (char*)d_ws;
  size_t off = 0;
  auto alloc = [&](size_t bytes)->void*{
    void* p = ws + off; off += (bytes + 255) & ~(size_t)255; return p;
  };
  u16*   wqt = (u16*)  alloc((size_t)KD_*D_*2);
  u16*   wkt = (u16*)  alloc((size_t)KD_*D_*2);
  u16*   wvt = (u16*)  alloc((size_t)DV_*DV_*2);
  u16*   qbf = (u16*)  alloc((size_t)BI_*KD_*2);
  u16*   kbf = (u16*)  alloc((size_t)MK_*KD_*2);
  u16*   yt  = (u16*)  alloc((size_t)B_*DV_*TJ_*2);
  u16*   Pb  = (u16*)  alloc((size_t)B_*T_*I_*J_*2);
  float* mb  = (float*)alloc((size_t)B_*T_*I_*4);
  float* zb  = (float*)alloc((size_t)B_*T_*I_*4);
  u16*   ubf = (u16*)  alloc((size_t)BI_*DV_*2);
  float* Fp  = (float*)alloc((size_t)4*BI_*DV_*4);     // final-gemm split-K partials (f32)
  u16*   Up  = (u16*)  alloc((size_t)8*BI_*DV_*2);     // passB partials (bf16), CH=8

  k_prep<<<4096 + 1280, 256, 0, stream>>>(memory_y, yt, Wq, Wk, Wv, wqt, wkt, wvt);
  k_proj<<<512 + 32, 256, 0, stream>>>(memory_x, input_seq, wkt, wqt, bk, bq, kbf, qbf);
  k_score<<<dim3(I_/64, T_, B_), 256, 0, stream>>>(qbf, kbf, Pb, mb, zb);
  k_passB<8><<<16*B_*8, 256, 0, stream>>>(Pb, mb, zb, yt, Up);
  k_reduce_u<8><<<(BI_*DV_/8)/256, 256, 0, stream>>>(Up, ubf);
  k_gemmF<<<dim3(BI_/64, DV_/64, 4), 256, 0, stream>>>(ubf, wvt, Fp);
  k_out<<<(BI_*DV_/4)/256, 256, 0, stream>>>(Fp, bv, out);
}

// Round 5
// 92.855 us; speedup vs baseline: 1.6869x; 1.2601x over previous
//
#include <hip/hip_runtime.h>
#include <cstdint>

#define B_ 4
#define I_ 512
#define T_ 32
#define J_ 256
#define D_ 512
#define DV_ 512
#define KD_ 64
#define TJ_ (T_*J_)      /* 8192 */
#define BI_ (B_*I_)      /* 2048 */
#define MK_ (B_*T_*J_)   /* 32768 */

typedef unsigned short u16;
typedef __attribute__((ext_vector_type(8))) u16 u16x8;
typedef __attribute__((ext_vector_type(4))) u16 u16x4;
typedef __attribute__((ext_vector_type(8))) short bf16x8;
typedef __attribute__((ext_vector_type(4))) float f32x4;

__device__ __forceinline__ u16 f2bf(float f){
  unsigned u = __float_as_uint(f);
  u += 0x7fffu + ((u >> 16) & 1u);
  return (u16)(u >> 16);
}
__device__ __forceinline__ float bf2f(u16 h){ return __uint_as_float(((unsigned)h) << 16); }

// async global->LDS, 16B per lane; LDS dest must be wave-uniform base + lane*16
#define GLD16(gsrc, ldst) __builtin_amdgcn_global_load_lds( \
    (const __attribute__((address_space(1))) unsigned int*)(gsrc), \
    (__attribute__((address_space(3))) unsigned int*)(ldst), 16, 0, 0)

// ---------------------------------------------------------------- prep: Y transpose tiles + all 3 weight transposes
__global__ __launch_bounds__(256) void k_prep(const float* __restrict__ Y, u16* __restrict__ Yt,
                                              const float* __restrict__ Wq, const float* __restrict__ Wk,
                                              const float* __restrict__ Wv, u16* __restrict__ wqt,
                                              u16* __restrict__ wkt, u16* __restrict__ wvt){
  __shared__ __align__(16) u16 tileT[64][72];
  int bid = blockIdx.x;
  int tid = threadIdx.x;
  if (bid < 4096){
    int kx = bid & 127, ny = (bid >> 7) & 7, b = bid >> 10;
    int k0 = kx*64, n0 = ny*64;
    #pragma unroll
    for (int s=0;s<4;++s){
      int idx = tid + s*256; int r = idx>>4, c4 = idx&15;
      const float4 v = *(const float4*)&Y[((size_t)b*TJ_ + k0 + r)*DV_ + n0 + c4*4];
      tileT[c4*4+0][r] = f2bf(v.x);
      tileT[c4*4+1][r] = f2bf(v.y);
      tileT[c4*4+2][r] = f2bf(v.z);
      tileT[c4*4+3][r] = f2bf(v.w);
    }
    __syncthreads();
    #pragma unroll
    for (int s=0;s<2;++s){
      int idx = tid + s*256; int rn = idx>>3, c8 = idx&7;
      *(u16x8*)&Yt[((size_t)b*DV_ + n0 + rn)*TJ_ + k0 + c8*8] = *(const u16x8*)&tileT[rn][c8*8];
    }
  } else {
    int gid = (bid - 4096)*256 + tid;
    if (gid < 32768){
      int n = gid >> 9, k = gid & 511;
      wqt[gid] = f2bf(Wq[(size_t)k*64 + n]);
    } else if (gid < 65536){
      int g = gid - 32768;
      int n = g >> 9, k = g & 511;
      wkt[g] = f2bf(Wk[(size_t)k*64 + n]);
    } else {
      int g = gid - 65536;
      int n = g >> 9, k = g & 511;
      wvt[g] = f2bf(Wv[(size_t)k*512 + n]);
    }
  }
}

// ---------------------------------------------------------------- merged Q+K projections, 32-row tiles, issue-early prefetch
// blocks [0,1024): K-proj; [1024,1088): Q-proj.
__global__ __launch_bounds__(256) void k_proj(const float* __restrict__ mx, const float* __restrict__ iseq,
                                              const u16* __restrict__ wkt, const u16* __restrict__ wqt,
                                              const float* __restrict__ bk, const float* __restrict__ bq,
                                              u16* __restrict__ kbf, u16* __restrict__ qbf){
  __shared__ __align__(16) u16 As[32][72];
  __shared__ __align__(16) u16 Bs[64][72];
  int bid = blockIdx.x;
  const float* A; const u16* Bt; const float* bias; u16* C; int row0;
  if (bid < 1024){ A = mx;   Bt = wkt; bias = bk; C = kbf; row0 = bid*32; }
  else           { A = iseq; Bt = wqt; bias = bq; C = qbf; row0 = (bid-1024)*32; }
  int tid = threadIdx.x;
  int lane = tid & 63, wv = tid >> 6;
  int lrow = lane & 15, lk8 = (lane >> 4) * 8;
  int mf = wv >> 1, nfb = (wv & 1) * 2;
  int ar = tid >> 4, ac4 = tid & 15;      // A: 32 rows x 16 float4 (2 passes? no: 512 slots, 2 loads)
  int br = tid >> 3, bc8 = tid & 7;       // B: 64 rows x 8 u16x8 (2 passes)
  f32x4 acc[2];
  acc[0] = (f32x4){0.f,0.f,0.f,0.f}; acc[1] = (f32x4){0.f,0.f,0.f,0.f};

  float4 fa[2][2]; u16x8 fb[2][2];
  // A tile: 32x64 f32 = 2048 f32 = 512 float4 -> 2 per thread (rows ar, ar+16... idx=tid+s*256: r=idx>>4)
  #define PROJ_LOAD(pp, k0) { \
    fa[pp][0] = *(const float4*)&A[(size_t)(row0 + ar)*512 + (k0) + ac4*4]; \
    fa[pp][1] = *(const float4*)&A[(size_t)(row0 + ar + 16)*512 + (k0) + ac4*4]; \
    fb[pp][0] = *(const u16x8*)&Bt[(size_t)br*512 + (k0) + bc8*8]; \
    fb[pp][1] = *(const u16x8*)&Bt[(size_t)(br+32)*512 + (k0) + bc8*8]; }

  PROJ_LOAD(0, 0)
  #pragma unroll
  for (int t=0;t<8;++t){
    const int p = t & 1;
    if (t) __syncthreads();
    if (t < 7) PROJ_LOAD(p^1, (t+1)*64)
    #pragma unroll
    for (int s=0;s<2;++s){
      u16x4 o; o[0]=f2bf(fa[p][s].x); o[1]=f2bf(fa[p][s].y); o[2]=f2bf(fa[p][s].z); o[3]=f2bf(fa[p][s].w);
      *(u16x4*)&As[ar + 16*s][ac4*4] = o;
      *(u16x8*)&Bs[br + 32*s][bc8*8] = fb[p][s];
    }
    __syncthreads();
    #pragma unroll
    for (int kk=0;kk<2;++kk){
      bf16x8 a = *(const bf16x8*)&As[mf*16 + lrow][kk*32 + lk8];
      #pragma unroll
      for (int n2=0;n2<2;++n2){
        bf16x8 bb = *(const bf16x8*)&Bs[(nfb+n2)*16 + lrow][kk*32 + lk8];
        acc[n2] = __builtin_amdgcn_mfma_f32_16x16x32_bf16(a, bb, acc[n2], 0, 0, 0);
      }
    }
  }
  #undef PROJ_LOAD
  #pragma unroll
  for (int n2=0;n2<2;++n2)
    #pragma unroll
    for (int r=0;r<4;++r){
      int row = row0 + mf*16 + (lane>>4)*4 + r;
      int col = (nfb+n2)*16 + lrow;
      C[(size_t)row*64 + col] = f2bf(acc[n2][r] + bias[col]);
    }
}

// ---------------------------------------------------------------- scores: per (b,t,i-tile of 64): S=Q*K^T, stats, P
__global__ __launch_bounds__(256) void k_score(const u16* __restrict__ Qbf, const u16* __restrict__ Kbf,
                                               u16* __restrict__ P, float* __restrict__ mb, float* __restrict__ zb){
  __shared__ __align__(16) u16 Qs[64][72];
  __shared__ __align__(16) u16 Ks[256][72];   // reused as Ps[64][264] after MFMA
  __shared__ float smax[4][64];
  __shared__ float ssum[4][64];
  __shared__ float mrow[64];
  int tid = threadIdx.x;
  int i0 = blockIdx.x*64, t = blockIdx.y, b = blockIdx.z;
  int lane = tid & 63, wv = tid >> 6;
  int lrow = lane & 15, lk = (lane >> 4) * 8;

  #pragma unroll
  for (int s=0;s<2;++s){
    int idx = tid + s*256; int r = idx>>3, c8 = idx&7;
    *(u16x8*)&Qs[r][c8*8] = *(const u16x8*)&Qbf[((size_t)b*I_ + i0 + r)*KD_ + c8*8];
  }
  #pragma unroll
  for (int s=0;s<8;++s){
    int idx = tid + s*256; int r = idx>>3, c8 = idx&7;
    *(u16x8*)&Ks[r][c8*8] = *(const u16x8*)&Kbf[(((size_t)b*T_ + t)*J_ + r)*KD_ + c8*8];
  }
  __syncthreads();

  f32x4 acc[4][4];
  #pragma unroll
  for (int i=0;i<4;++i)
    #pragma unroll
    for (int j=0;j<4;++j) acc[i][j] = (f32x4){0.f,0.f,0.f,0.f};

  #pragma unroll
  for (int kk=0;kk<2;++kk){
    bf16x8 a[4], bb[4];
    #pragma unroll
    for (int mf=0;mf<4;++mf) a[mf] = *(const bf16x8*)&Qs[mf*16 + lrow][kk*32 + lk];
    #pragma unroll
    for (int nf=0;nf<4;++nf) bb[nf] = *(const bf16x8*)&Ks[wv*64 + nf*16 + lrow][kk*32 + lk];
    #pragma unroll
    for (int mf=0;mf<4;++mf)
      #pragma unroll
      for (int nf=0;nf<4;++nf)
        acc[mf][nf] = __builtin_amdgcn_mfma_f32_16x16x32_bf16(a[mf], bb[nf], acc[mf][nf], 0, 0, 0);
  }

  #pragma unroll
  for (int mf=0;mf<4;++mf)
    #pragma unroll
    for (int r=0;r<4;++r){
      float v = acc[mf][0][r];
      #pragma unroll
      for (int nf=1;nf<4;++nf) v = fmaxf(v, acc[mf][nf][r]);
      v = fmaxf(v, __shfl_xor(v, 1));
      v = fmaxf(v, __shfl_xor(v, 2));
      v = fmaxf(v, __shfl_xor(v, 4));
      v = fmaxf(v, __shfl_xor(v, 8));
      if (lrow == 0) smax[wv][mf*16 + (lane>>4)*4 + r] = v;
    }
  __syncthreads();
  if (tid < 64){
    float m = fmaxf(fmaxf(smax[0][tid], smax[1][tid]), fmaxf(smax[2][tid], smax[3][tid]));
    mrow[tid] = m;
    mb[((size_t)b*T_ + t)*I_ + i0 + tid] = m;
  }
  __syncthreads();

  #pragma unroll
  for (int mf=0;mf<4;++mf)
    #pragma unroll
    for (int r=0;r<4;++r){
      int row = mf*16 + (lane>>4)*4 + r;
      float M = mrow[row];
      float ssm = 0.f;
      #pragma unroll
      for (int nf=0;nf<4;++nf){
        float p = __expf(0.125f*(acc[mf][nf][r] - M));
        acc[mf][nf][r] = p;
        ssm += p;
      }
      ssm += __shfl_xor(ssm, 1);
      ssm += __shfl_xor(ssm, 2);
      ssm += __shfl_xor(ssm, 4);
      ssm += __shfl_xor(ssm, 8);
      if (lrow == 0) ssum[wv][row] = ssm;
    }
  __syncthreads();
  if (tid < 64){
    float z = ssum[0][tid] + ssum[1][tid] + ssum[2][tid] + ssum[3][tid];
    zb[((size_t)b*T_ + t)*I_ + i0 + tid] = z;
  }

  u16* Ps = &Ks[0][0];              // stride 264 u16
  #pragma unroll
  for (int mf=0;mf<4;++mf)
    #pragma unroll
    for (int nf=0;nf<4;++nf)
      #pragma unroll
      for (int r=0;r<4;++r){
        int row = mf*16 + (lane>>4)*4 + r;
        int col = wv*64 + nf*16 + lrow;
        Ps[row*264 + col] = f2bf(acc[mf][nf][r]);
      }
  __syncthreads();
  #pragma unroll
  for (int s=0;s<8;++s){
    int idx = tid + s*256; int r = idx>>5, c8 = idx&31;
    *(u16x8*)&P[(((size_t)b*T_ + t)*I_ + i0 + r)*J_ + c8*8] = *(const u16x8*)&Ps[r*264 + c8*8];
  }
}

// ---------------------------------------------------------------- U = sum_t c_t*(P_t @ Y_t); level-2 softmax in-block.
// global_load_lds staging, unpadded [128][64] LDS with XOR slot-swizzle (phys slot = lin slot ^ (row&7)).
template<int CH>
__global__ __launch_bounds__(256,2) void k_passB(const u16* __restrict__ P, const float* __restrict__ mbp,
                                                 const float* __restrict__ zbp, const u16* __restrict__ Yt,
                                                 u16* __restrict__ Up){
  constexpr int TPC = T_/CH;
  __shared__ __align__(16) u16 As[128*64];
  __shared__ __align__(16) u16 Bs[128*64];
  __shared__ float cs[TPC][128];
  int tid = threadIdx.x;
  int lane = tid & 63, wv = tid >> 6, wm = wv >> 1, wn = wv & 1;
  int lrow = lane & 15;

  // XCD swizzle: 16 blocks sharing a (b,ch) chunk land on one XCD
  int NWG = 16*B_*CH;
  int per = NWG >> 3;
  int logical = (blockIdx.x & 7)*per + (blockIdx.x >> 3);
  int group = logical >> 4, within = logical & 15;
  int ix = within & 3, ny = within >> 2;
  int b = group / CH, ch = group % CH;
  int i0 = ix*128, n0 = ny*128;

  if (tid < 128){
    int i = i0 + tid;
    float w[T_];
    float lmax = -3.0e38f;
    #pragma unroll
    for (int t=0;t<T_;++t){
      float mt = 0.125f * mbp[((size_t)b*T_ + t)*I_ + i];
      w[t] = mt;
      lmax = fmaxf(lmax, mt);
    }
    float W = 0.f;
    #pragma unroll
    for (int t=0;t<T_;++t){ float e = __expf(w[t] - lmax); w[t] = e; W += e; }
    float inv = 1.f / W;
    #pragma unroll
    for (int tt=0;tt<TPC;++tt)
      cs[tt][tid] = w[ch*TPC+tt] * inv / zbp[((size_t)b*T_ + ch*TPC + tt)*I_ + i];
  }
  __syncthreads();

  int l8 = lane >> 3, sl = lane & 7;     // staging: 8 rows x 8 slots per wave-instr

  f32x4 acc[4][4];
  #pragma unroll
  for (int i=0;i<4;++i)
    #pragma unroll
    for (int j=0;j<4;++j) acc[i][j] = (f32x4){0.f,0.f,0.f,0.f};

  for (int tt = 0; tt < TPC; ++tt){
    int t = ch*TPC + tt;
    const u16* Pbase = &P[(((size_t)b*T_ + t)*I_ + i0)*J_];
    const u16* Ybase = &Yt[((size_t)b*DV_ + n0)*TJ_ + (size_t)t*J_];
    f32x4 at[4][4];
    #pragma unroll
    for (int i=0;i<4;++i)
      #pragma unroll
      for (int j=0;j<4;++j) at[i][j] = (f32x4){0.f,0.f,0.f,0.f};

    for (int st = 0; st < 4; ++st){
      int j0 = st*64;
      if (tt | st) __syncthreads();
      #pragma unroll
      for (int s=0;s<4;++s){
        int row = (wv*4+s)*8 + l8;
        int colA = j0 + ((sl ^ (row & 7)) << 3);
        GLD16(Pbase + (size_t)row*J_ + colA, (u16*)As + (wv*4+s)*512);
        GLD16(Ybase + (size_t)row*TJ_ + colA, (u16*)Bs + (wv*4+s)*512);
      }
      __syncthreads();
      #pragma unroll
      for (int kk=0;kk<2;++kk){
        bf16x8 a[4], bb[4];
        #pragma unroll
        for (int mf=0;mf<4;++mf){
          int ar = wm*64 + mf*16 + lrow;
          int off = ar*128 + ((kk*64 + (lane>>4)*16) ^ ((ar & 7) << 4));
          a[mf] = *(const bf16x8*)((const char*)As + off);
        }
        #pragma unroll
        for (int nf=0;nf<4;++nf){
          int br = wn*64 + nf*16 + lrow;
          int off = br*128 + ((kk*64 + (lane>>4)*16) ^ ((br & 7) << 4));
          bb[nf] = *(const bf16x8*)((const char*)Bs + off);
        }
        #pragma unroll
        for (int mf=0;mf<4;++mf)
          #pragma unroll
          for (int nf=0;nf<4;++nf)
            at[mf][nf] = __builtin_amdgcn_mfma_f32_16x16x32_bf16(a[mf], bb[nf], at[mf][nf], 0, 0, 0);
      }
    }
    #pragma unroll
    for (int mf=0;mf<4;++mf)
      #pragma unroll
      for (int r=0;r<4;++r){
        float c = cs[tt][wm*64 + mf*16 + (lane>>4)*4 + r];
        #pragma unroll
        for (int nf=0;nf<4;++nf)
          acc[mf][nf][r] += c * at[mf][nf][r];
      }
  }

  #pragma unroll
  for (int mf=0;mf<4;++mf)
    #pragma unroll
    for (int nf=0;nf<4;++nf)
      #pragma unroll
      for (int r=0;r<4;++r){
        int row = i0 + wm*64 + mf*16 + (lane>>4)*4 + r;
        int col = n0 + wn*64 + nf*16 + lrow;
        Up[(size_t)ch*BI_*DV_ + ((size_t)b*I_ + row)*DV_ + col] = f2bf(acc[mf][nf][r]);
      }
}

// ---------------------------------------------------------------- final: out = (sum_ch Up_ch) @ Wv^T + bv  (f32 out)
// 32x64 tiles, XCD-swizzled so the 8 col-blocks sharing an A-chunk co-reside; A = inline sum of CH bf16 partials.
template<int CH>
__global__ __launch_bounds__(256) void k_final(const u16* __restrict__ Up, const u16* __restrict__ Bt,
                                               const float* __restrict__ bv, float* __restrict__ out){
  __shared__ __align__(16) u16 As[32][72];
  __shared__ __align__(16) u16 Bs[64][72];
  int tid = threadIdx.x;
  int lane = tid & 63, wv = tid >> 6;
  int lrow = lane & 15, lk8 = (lane >> 4) * 8;
  int bid = blockIdx.x;
  int swz = (bid & 7)*64 + (bid >> 3);        // 512 blocks, bijective
  int row0 = (swz >> 3)*32, col0 = (swz & 7)*64;
  int mf = wv >> 1, nfb = (wv & 1)*2;
  const size_t S = (size_t)BI_*DV_;
  int ar = tid >> 3, ac8 = tid & 7;           // A: 32 rows x 8 u16x8
  f32x4 acc[2];
  acc[0] = (f32x4){0.f,0.f,0.f,0.f}; acc[1] = (f32x4){0.f,0.f,0.f,0.f};

  u16x8 pa[2][CH]; u16x8 rb[2][2];
  #define FIN_LOAD(pp, k0) { \
    _Pragma("unroll") \
    for (int c=0;c<CH;++c) pa[pp][c] = *(const u16x8*)&Up[(size_t)c*S + (size_t)(row0+ar)*512 + (k0) + ac8*8]; \
    _Pragma("unroll") \
    for (int s=0;s<2;++s) rb[pp][s] = *(const u16x8*)&Bt[(size_t)(col0 + (tid>>3) + 32*s)*512 + (k0) + ac8*8]; }

  FIN_LOAD(0, 0)
  #pragma unroll
  for (int t=0;t<8;++t){
    const int p = t & 1;
    if (t) __syncthreads();
    if (t < 7) FIN_LOAD(p^1, (t+1)*64)
    u16x8 o;
    #pragma unroll
    for (int e=0;e<8;++e){
      float v = 0.f;
      #pragma unroll
      for (int c=0;c<CH;++c) v += bf2f(pa[p][c][e]);
      o[e] = f2bf(v);
    }
    *(u16x8*)&As[ar][ac8*8] = o;
    #pragma unroll
    for (int s=0;s<2;++s) *(u16x8*)&Bs[(tid>>3) + 32*s][ac8*8] = rb[p][s];
    __syncthreads();
    #pragma unroll
    for (int kk=0;kk<2;++kk){
      bf16x8 a = *(const bf16x8*)&As[mf*16 + lrow][kk*32 + lk8];
      #pragma unroll
      for (int n2=0;n2<2;++n2){
        bf16x8 bb = *(const bf16x8*)&Bs[(nfb+n2)*16 + lrow][kk*32 + lk8];
        acc[n2] = __builtin_amdgcn_mfma_f32_16x16x32_bf16(a, bb, acc[n2], 0, 0, 0);
      }
    }
  }
  #undef FIN_LOAD
  #pragma unroll
  for (int n2=0;n2<2;++n2)
    #pragma unroll
    for (int r=0;r<4;++r){
      int row = row0 + mf*16 + (lane>>4)*4 + r;
      int col = col0 + (nfb+n2)*16 + lrow;
      out[(size_t)row*DV_ + col] = acc[n2][r] + bv[col];
    }
}

// ----------------------------------------------------------------
extern "C" void kernel_launch(void* const* d_in, const int* in_sizes, int n_in,
                              void* d_out, int out_size, void* d_ws, size_t ws_size,
                              hipStream_t stream){
  const float* input_seq = (const float*)d_in[0];
  const float* memory_x  = (const float*)d_in[1];
  const float* memory_y  = (const float*)d_in[2];
  const float* Wq = (const float*)d_in[3];
  const float* bq = (const float*)d_in[4];
  const float* Wk = (const float*)d_in[5];
  const float* bk = (const float*)d_in[6];
  const float* Wv = (const float*)d_in[7];
  const float* bv = (const float*)d_in[8];
  float* out = (float*)d_out;

  char* ws = (char*)d_ws;
  size_t off = 0;
  auto alloc = [&](size_t bytes)->void*{
    void* p = ws + off; off += (bytes + 255) & ~(size_t)255; return p;
  };
  u16*   wqt = (u16*)  alloc((size_t)KD_*D_*2);
  u16*   wkt = (u16*)  alloc((size_t)KD_*D_*2);
  u16*   wvt = (u16*)  alloc((size_t)DV_*DV_*2);
  u16*   qbf = (u16*)  alloc((size_t)BI_*KD_*2);
  u16*   kbf = (u16*)  alloc((size_t)MK_*KD_*2);
  u16*   yt  = (u16*)  alloc((size_t)B_*DV_*TJ_*2);
  u16*   Pb  = (u16*)  alloc((size_t)B_*T_*I_*J_*2);
  float* mb  = (float*)alloc((size_t)B_*T_*I_*4);
  float* zb  = (float*)alloc((size_t)B_*T_*I_*4);
  u16*   Up  = (u16*)  alloc((size_t)8*BI_*DV_*2);     // passB partials (bf16), CH=8

  k_prep<<<4096 + 1280, 256, 0, stream>>>(memory_y, yt, Wq, Wk, Wv, wqt, wkt, wvt);
  k_proj<<<1024 + 64, 256, 0, stream>>>(memory_x, input_seq, wkt, wqt, bk, bq, kbf, qbf);
  k_score<<<dim3(I_/64, T_, B_), 256, 0, stream>>>(qbf, kbf, Pb, mb, zb);
  k_passB<8><<<16*B_*8, 256, 0, stream>>>(Pb, mb, zb, yt, Up);
  k_final<8><<<512, 256, 0, stream>>>(Up, wvt, bv, out);
}